// Round 31
// baseline (85.302 us; speedup 1.0000x reference)
//
#include <hip/hip_runtime.h>
#include <hip/hip_bf16.h>

typedef __bf16 bf16;
typedef __attribute__((ext_vector_type(4)))  __bf16 bf16x4;
typedef __attribute__((ext_vector_type(8)))  __bf16 bf16x8;
typedef __attribute__((ext_vector_type(4)))  float  f32x4;
typedef __attribute__((ext_vector_type(16))) float  f32x16;
typedef __attribute__((ext_vector_type(4)))  unsigned u32x4;

#define NN   4096
#define INF  256
#define HH   8
#define FF   64
#define HF   512
#define ALPHA_ 0.2f
#define NW   128            // bitmask words per row (4096/32)

// Tiled Wh layout: WhTt[head][jblk=j/16][row=f(64)][jin=j%16], bf16.

// ---------------------------------------------------------------------------
// Kernel 0: pack adj (int32 0/1) -> bitmask, 64 MB -> 2 MB. Pure BW.
// ---------------------------------------------------------------------------
__global__ __launch_bounds__(256) void k_pack(const int* __restrict__ adj,
                                              unsigned* __restrict__ bits)
{
    const int t   = blockIdx.x * 256 + threadIdx.x;       // 0 .. 524287
    const int row = t >> 7;
    const int jw  = t & 127;
    const int* p  = adj + (size_t)row * NN + (jw << 5);
    unsigned m = 0u;
#pragma unroll
    for (int k = 0; k < 8; ++k) {
        const int4 v = *(const int4*)(p + (k << 2));
        m |= (v.x != 0 ? 1u : 0u) << (4 * k);
        m |= (v.y != 0 ? 1u : 0u) << (4 * k + 1);
        m |= (v.z != 0 ? 1u : 0u) << (4 * k + 2);
        m |= (v.w != 0 ? 1u : 0u) << (4 * k + 3);
    }
    bits[t] = m;
}

// ---------------------------------------------------------------------------
// Kernel 1: Wh = h @ W, written in TILED layout. (verified r18)
// ---------------------------------------------------------------------------
__global__ __launch_bounds__(256) void k_wht(const float* __restrict__ A,
                                             const float* __restrict__ W,
                                             bf16* __restrict__ WhTt)
{
    __shared__ bf16 Bs[64][36];
    const int bid = blockIdx.x;
    const int mt = (bid >> 3) << 6;
    const int nt = (bid & 7) << 6;
    const int tid = threadIdx.x;
    const int wv  = tid >> 6;
    const int l   = tid & 63;
    const int l15 = l & 15;
    const int lq  = l >> 4;

    f32x4 acc[4];
#pragma unroll
    for (int nb = 0; nb < 4; ++nb) acc[nb] = (f32x4)0.0f;

    const int krow = tid >> 3;
    const int ncol = (tid & 7) << 3;

    for (int kb = 0; kb < INF; kb += 32) {
        const float4 w0 = *(const float4*)&W[(kb + krow) * HF + nt + ncol];
        const float4 w1 = *(const float4*)&W[(kb + krow) * HF + nt + ncol + 4];
        __syncthreads();
        Bs[ncol + 0][krow] = (bf16)w0.x; Bs[ncol + 1][krow] = (bf16)w0.y;
        Bs[ncol + 2][krow] = (bf16)w0.z; Bs[ncol + 3][krow] = (bf16)w0.w;
        Bs[ncol + 4][krow] = (bf16)w1.x; Bs[ncol + 5][krow] = (bf16)w1.y;
        Bs[ncol + 6][krow] = (bf16)w1.z; Bs[ncol + 7][krow] = (bf16)w1.w;
        __syncthreads();

        const float* pA = A + (mt + wv * 16 + l15) * INF + kb + (lq << 2);
        const float4 a0 = *(const float4*)pA;
        const float4 a1 = *(const float4*)(pA + 16);
        bf16x8 af;
        af[0] = (bf16)a0.x; af[1] = (bf16)a0.y; af[2] = (bf16)a0.z; af[3] = (bf16)a0.w;
        af[4] = (bf16)a1.x; af[5] = (bf16)a1.y; af[6] = (bf16)a1.z; af[7] = (bf16)a1.w;

#pragma unroll
        for (int nb = 0; nb < 4; ++nb) {
            const bf16* pB = &Bs[(nb << 4) + l15][lq << 2];
            bf16x4 blo = *(const bf16x4*)pB;
            bf16x4 bhi = *(const bf16x4*)(pB + 16);
            bf16x8 bf = __builtin_shufflevector(blo, bhi, 0,1,2,3,4,5,6,7);
            acc[nb] = __builtin_amdgcn_mfma_f32_16x16x32_bf16(af, bf, acc[nb], 0, 0, 0);
        }
    }

    const int m0 = mt + wv * 16 + (lq << 2);      // node index j (4 consecutive)
#pragma unroll
    for (int nb = 0; nb < 4; ++nb) {
        const int col = nt + (nb << 4) + l15;     // feature 0..511
        bf16x4 o;
#pragma unroll
        for (int r = 0; r < 4; ++r) o[r] = (bf16)acc[nb][r];
        const int hd_ = col >> 6, row_ = col & 63;
        bf16* dst = WhTt + (((size_t)(hd_ << 8) + (m0 >> 4)) << 10)
                  + (row_ << 4) + (m0 & 15);
        *(bf16x4*)dst = o;
    }
}

// ---------------------------------------------------------------------------
// Kernel 2: score tables. e1-cancellation (verified r30): c = exp(-0.8*t1);
// weights max(e2, c*f2). E2/F2 bf16.
// ---------------------------------------------------------------------------
__global__ __launch_bounds__(256) void k_scores(const bf16* __restrict__ WhTt,
                                                const float* __restrict__ a,
                                                float* __restrict__ cF,
                                                bf16* __restrict__ E2b, bf16* __restrict__ F2b)
{
    const int h = blockIdx.x >> 4;
    const int i = ((blockIdx.x & 15) << 8) + threadIdx.x;
    const bf16* wb = WhTt + (((size_t)(h << 8) + (i >> 4)) << 10) + (i & 15);
    float t1 = 0.f, t2 = 0.f;
#pragma unroll 16
    for (int f = 0; f < FF; ++f) {
        float w = (float)wb[f << 4];
        t1 += w * a[h * 128 + f];
        t2 += w * a[h * 128 + 64 + f];
    }
    cF[h * NN + i]  = __expf(-0.8f * t1);
    E2b[h * NN + i] = (bf16)__expf(t2);
    F2b[h * NN + i] = (bf16)__expf(ALPHA_ * t2);
}

// ---------------------------------------------------------------------------
// Kernel 3 v18: merge of the two measured-best variants:
//   v16 (70.7us, VALU 42%): 2-deep rolled + LUT masking + MFMA-den (fixed
//       row extraction), LDS 17.5KB
//   v17 (e1-cancellation): max(ea, c*fa) -- 8 fewer muls/stage
// Never tested together. VGPR: v16 measured 68, -1 scalar ~= 67 <= 85.
// ---------------------------------------------------------------------------
#define DECL_STAGE(P) \
    unsigned P##_bw; \
    bf16x8 P##_ea, P##_fa, P##_b0, P##_b1;

#define LOAD_STAGE(P, s) do { \
    const int jb_ = jwb + ((s) << 4); \
    const bf16* tb_ = whb + ((s) << 10); \
    P##_bw = (unsigned)bitrow16[(s)]; \
    P##_ea = *(const bf16x8*)(e2r + jb_); \
    P##_fa = *(const bf16x8*)(f2r + jb_); \
    P##_b0 = *(const bf16x8*)(tb_ + (l31 << 4) + (lh << 3)); \
    P##_b1 = *(const bf16x8*)(tb_ + ((32 + l31) << 4) + (lh << 3)); \
} while (0)

#define COMPUTE_STAGE(P) do { \
    const unsigned bsel_ = (P##_bw >> sh0) & 0xffu; \
    bf16x8 pa_; \
    _Pragma("unroll") \
    for (int k_ = 0; k_ < 8; ++k_) { \
        const float w_ = fmaxf((float)P##_ea[k_], c * (float)P##_fa[k_]); \
        pa_[k_] = (bf16)w_; \
    } \
    u32x4 pm_ = __builtin_bit_cast(u32x4, pa_); \
    _Pragma("unroll") \
    for (int d_ = 0; d_ < 4; ++d_) pm_[d_] &= lut4[(bsel_ >> (2 * d_)) & 3u]; \
    pa_ = __builtin_bit_cast(bf16x8, pm_); \
    acc0 = __builtin_amdgcn_mfma_f32_32x32x16_bf16(pa_, P##_b0, acc0, 0, 0, 0); \
    acc1 = __builtin_amdgcn_mfma_f32_32x32x16_bf16(pa_, P##_b1, acc1, 0, 0, 0); \
    accd = __builtin_amdgcn_mfma_f32_32x32x16_bf16(pa_, ones, accd, 0, 0, 0); \
} while (0)

__global__ __launch_bounds__(512, 3) void k_gat(const unsigned* __restrict__ bits,
                                                const bf16* __restrict__ WhTt,
                                                const float* __restrict__ cF,
                                                const bf16* __restrict__ E2b, const bf16* __restrict__ F2b,
                                                const float* __restrict__ bias,
                                                float* __restrict__ out)
{
    __shared__ float red2[2][32][64];    // 16 KB
    __shared__ float dred[8][32];        // 1 KB
    __shared__ unsigned lut4[4];

    const int bid = blockIdx.x;
    const int hd = bid & 7;              // head 0..7 (== XCD -> L2-local slice)
    const int ib = bid >> 3;             // i-block 0..127

    const int tid = threadIdx.x;
    const int wv  = tid >> 6;            // 0..7 = j-split
    const int l   = tid & 63;
    const int l31 = l & 31;
    const int lh  = l >> 5;

    if (tid < 4) lut4[tid] = (tid & 1 ? 0x0000FFFFu : 0u) | (tid & 2 ? 0xFFFF0000u : 0u);
    __syncthreads();

    const int i = (ib << 5) + l31;

    const float c = cF[hd * NN + i];

    f32x16 acc0 = (f32x16)0.f, acc1 = (f32x16)0.f, accd = (f32x16)0.f;

    bf16x8 ones;
#pragma unroll
    for (int k = 0; k < 8; ++k) ones[k] = (bf16)1.0f;

    // 16-bit bit-words: word s covers j = wv*512 + s*16 .. +15
    const unsigned short* bitrow16 =
        (const unsigned short*)(bits + (size_t)i * NW) + (wv << 5);
    const bf16* e2r = E2b + hd * NN;
    const bf16* f2r = F2b + hd * NN;
    // head base of tiled Wh; wave's jblk = wv*32 + s
    const bf16* whb = WhTt + ((size_t)hd << 18) + ((size_t)(wv << 5) << 10);

    const int jwb = (wv << 9) + (lh << 3);   // wave j-base + lane half
    const int sh0 = lh << 3;                 // byte select within 16-bit word

    DECL_STAGE(A); DECL_STAGE(B);

    LOAD_STAGE(A, 0);
#pragma unroll 1
    for (int t = 0; t < 15; ++t) {
        LOAD_STAGE(B, 2 * t + 1); COMPUTE_STAGE(A);
        LOAD_STAGE(A, 2 * t + 2); COMPUTE_STAGE(B);
    }
    LOAD_STAGE(B, 31); COMPUTE_STAGE(A); COMPUTE_STAGE(B);

    // ---- den extraction: row m = (r&3)+8*(r>>2)+4*lh (verified r27) -------
    if (l31 == 0) {
#pragma unroll
        for (int r = 0; r < 16; ++r) {
            dred[wv][(r & 3) + 8 * (r >> 2) + 4 * lh] = accd[r];
        }
    }

    // ---- acc reduction: 2-buffer pairwise tree ---------------------------
    // C/D layout: col = l&31 (feature), row = (r&3) + 8*(r>>2) + 4*lh (i_loc)
    if (wv < 2) {
        float* rb = &red2[wv][0][0];
#pragma unroll
        for (int g = 0; g < 4; ++g) {
            const int ir = (g << 3) + (lh << 2);
#pragma unroll
            for (int r = 0; r < 4; ++r) {
                rb[(ir + r) * 64 + l31     ] = acc0[4*g + r];
                rb[(ir + r) * 64 + 32 + l31] = acc1[4*g + r];
            }
        }
    }
    __syncthreads();
    if (wv == 2 || wv == 3) {
        float* rb = &red2[wv - 2][0][0];
#pragma unroll
        for (int g = 0; g < 4; ++g) {
            const int ir = (g << 3) + (lh << 2);
#pragma unroll
            for (int r = 0; r < 4; ++r) {
                rb[(ir + r) * 64 + l31     ] += acc0[4*g + r];
                rb[(ir + r) * 64 + 32 + l31] += acc1[4*g + r];
            }
        }
    }
    __syncthreads();
    if (wv == 4 || wv == 5) {
        float* rb = &red2[wv - 4][0][0];
#pragma unroll
        for (int g = 0; g < 4; ++g) {
            const int ir = (g << 3) + (lh << 2);
#pragma unroll
            for (int r = 0; r < 4; ++r) {
                rb[(ir + r) * 64 + l31     ] += acc0[4*g + r];
                rb[(ir + r) * 64 + 32 + l31] += acc1[4*g + r];
            }
        }
    }
    __syncthreads();
    if (wv == 6 || wv == 7) {
        float* rb = &red2[wv - 6][0][0];
#pragma unroll
        for (int g = 0; g < 4; ++g) {
            const int ir = (g << 3) + (lh << 2);
#pragma unroll
            for (int r = 0; r < 4; ++r) {
                rb[(ir + r) * 64 + l31     ] += acc0[4*g + r];
                rb[(ir + r) * 64 + 32 + l31] += acc1[4*g + r];
            }
        }
    }
    __syncthreads();

    // ---- normalize + bias + store (buf0+buf1 folded here) ----------------
    const int iloc = tid >> 4;           // 0..31
    const int c0   = (tid & 15) << 2;    // 0..60, 4 cols per thread
    const float dsum = dred[0][iloc] + dred[1][iloc] + dred[2][iloc] + dred[3][iloc]
                     + dred[4][iloc] + dred[5][iloc] + dred[6][iloc] + dred[7][iloc];
    const float rd = 1.0f / dsum;
    f32x4 o;
#pragma unroll
    for (int r = 0; r < 4; ++r) {
        const float sv = red2[0][iloc][c0 + r] + red2[1][iloc][c0 + r];
        o[r] = sv * rd + bias[(hd << 6) + c0 + r];
    }
    *(f32x4*)&out[(size_t)((ib << 5) + iloc) * HF + (hd << 6) + c0] = o;
}

// ---------------------------------------------------------------------------
extern "C" void kernel_launch(void* const* d_in, const int* in_sizes, int n_in,
                              void* d_out, int out_size, void* d_ws, size_t ws_size,
                              hipStream_t stream) {
    const float* h    = (const float*)d_in[0];
    const int*   adj  = (const int*)d_in[1];
    const float* W    = (const float*)d_in[2];
    const float* a    = (const float*)d_in[3];
    const float* bias = (const float*)d_in[4];
    float* out = (float*)d_out;

    char* ws = (char*)d_ws;
    bf16*     WhTt = (bf16*)ws;                                   // 4 MB tiled
    float*    cF   = (float*)(ws + (size_t)(4 << 20));            // 128 KB
    bf16*     E2b  = (bf16*)(cF + HH * NN);                       // 64 KB
    bf16*     F2b  = E2b + HH * NN;                               // 64 KB
    unsigned* bits = (unsigned*)(ws + (size_t)(4 << 20) + (384 << 10)); // 2 MB

    hipLaunchKernelGGL(k_pack,   dim3(2048), dim3(256), 0, stream, adj, bits);
    hipLaunchKernelGGL(k_wht,    dim3(512),  dim3(256), 0, stream, h, W, WhTt);
    hipLaunchKernelGGL(k_scores, dim3(128),  dim3(256), 0, stream, WhTt, a, cF, E2b, F2b);
    hipLaunchKernelGGL(k_gat,    dim3(1024), dim3(512), 0, stream, bits, WhTt, cF, E2b, F2b, bias, out);
}

// Round 32
// 79.179 us; speedup vs baseline: 1.0773x; 1.0773x over previous
//
#include <hip/hip_runtime.h>
#include <hip/hip_bf16.h>

typedef __bf16 bf16;
typedef __attribute__((ext_vector_type(4)))  __bf16 bf16x4;
typedef __attribute__((ext_vector_type(8)))  __bf16 bf16x8;
typedef __attribute__((ext_vector_type(4)))  float  f32x4;
typedef __attribute__((ext_vector_type(16))) float  f32x16;

#define NN   4096
#define INF  256
#define HH   8
#define FF   64
#define HF   512
#define ALPHA_ 0.2f
#define NW   128            // bitmask words per row (4096/32)

// Tiled Wh layout: WhTt[head][jblk=j/16][row=f(64)][jin=j%16], bf16.

// ---------------------------------------------------------------------------
// Kernel 0: pack adj (int32 0/1) -> bitmask, 64 MB -> 2 MB. Pure BW.
// ---------------------------------------------------------------------------
__global__ __launch_bounds__(256) void k_pack(const int* __restrict__ adj,
                                              unsigned* __restrict__ bits)
{
    const int t   = blockIdx.x * 256 + threadIdx.x;       // 0 .. 524287
    const int row = t >> 7;
    const int jw  = t & 127;
    const int* p  = adj + (size_t)row * NN + (jw << 5);
    unsigned m = 0u;
#pragma unroll
    for (int k = 0; k < 8; ++k) {
        const int4 v = *(const int4*)(p + (k << 2));
        m |= (v.x != 0 ? 1u : 0u) << (4 * k);
        m |= (v.y != 0 ? 1u : 0u) << (4 * k + 1);
        m |= (v.z != 0 ? 1u : 0u) << (4 * k + 2);
        m |= (v.w != 0 ? 1u : 0u) << (4 * k + 3);
    }
    bits[t] = m;
}

// ---------------------------------------------------------------------------
// Kernel 1: Wh = h @ W, written in TILED layout. (verified r18)
// ---------------------------------------------------------------------------
__global__ __launch_bounds__(256) void k_wht(const float* __restrict__ A,
                                             const float* __restrict__ W,
                                             bf16* __restrict__ WhTt)
{
    __shared__ bf16 Bs[64][36];
    const int bid = blockIdx.x;
    const int mt = (bid >> 3) << 6;
    const int nt = (bid & 7) << 6;
    const int tid = threadIdx.x;
    const int wv  = tid >> 6;
    const int l   = tid & 63;
    const int l15 = l & 15;
    const int lq  = l >> 4;

    f32x4 acc[4];
#pragma unroll
    for (int nb = 0; nb < 4; ++nb) acc[nb] = (f32x4)0.0f;

    const int krow = tid >> 3;
    const int ncol = (tid & 7) << 3;

    for (int kb = 0; kb < INF; kb += 32) {
        const float4 w0 = *(const float4*)&W[(kb + krow) * HF + nt + ncol];
        const float4 w1 = *(const float4*)&W[(kb + krow) * HF + nt + ncol + 4];
        __syncthreads();
        Bs[ncol + 0][krow] = (bf16)w0.x; Bs[ncol + 1][krow] = (bf16)w0.y;
        Bs[ncol + 2][krow] = (bf16)w0.z; Bs[ncol + 3][krow] = (bf16)w0.w;
        Bs[ncol + 4][krow] = (bf16)w1.x; Bs[ncol + 5][krow] = (bf16)w1.y;
        Bs[ncol + 6][krow] = (bf16)w1.z; Bs[ncol + 7][krow] = (bf16)w1.w;
        __syncthreads();

        const float* pA = A + (mt + wv * 16 + l15) * INF + kb + (lq << 2);
        const float4 a0 = *(const float4*)pA;
        const float4 a1 = *(const float4*)(pA + 16);
        bf16x8 af;
        af[0] = (bf16)a0.x; af[1] = (bf16)a0.y; af[2] = (bf16)a0.z; af[3] = (bf16)a0.w;
        af[4] = (bf16)a1.x; af[5] = (bf16)a1.y; af[6] = (bf16)a1.z; af[7] = (bf16)a1.w;

#pragma unroll
        for (int nb = 0; nb < 4; ++nb) {
            const bf16* pB = &Bs[(nb << 4) + l15][lq << 2];
            bf16x4 blo = *(const bf16x4*)pB;
            bf16x4 bhi = *(const bf16x4*)(pB + 16);
            bf16x8 bf = __builtin_shufflevector(blo, bhi, 0,1,2,3,4,5,6,7);
            acc[nb] = __builtin_amdgcn_mfma_f32_16x16x32_bf16(af, bf, acc[nb], 0, 0, 0);
        }
    }

    const int m0 = mt + wv * 16 + (lq << 2);      // node index j (4 consecutive)
#pragma unroll
    for (int nb = 0; nb < 4; ++nb) {
        const int col = nt + (nb << 4) + l15;     // feature 0..511
        bf16x4 o;
#pragma unroll
        for (int r = 0; r < 4; ++r) o[r] = (bf16)acc[nb][r];
        const int hd_ = col >> 6, row_ = col & 63;
        bf16* dst = WhTt + (((size_t)(hd_ << 8) + (m0 >> 4)) << 10)
                  + (row_ << 4) + (m0 & 15);
        *(bf16x4*)dst = o;
    }
}

// ---------------------------------------------------------------------------
// Kernel 2: score tables. e1-CANCELLATION: softmax is row-scale invariant,
// so store c = f1/e1 = exp(-0.8*t1); weights become max(e2, c*f2).
// ---------------------------------------------------------------------------
__global__ __launch_bounds__(256) void k_scores(const bf16* __restrict__ WhTt,
                                                const float* __restrict__ a,
                                                float* __restrict__ cF,
                                                bf16* __restrict__ E2b, bf16* __restrict__ F2b)
{
    const int h = blockIdx.x >> 4;
    const int i = ((blockIdx.x & 15) << 8) + threadIdx.x;
    const bf16* wb = WhTt + (((size_t)(h << 8) + (i >> 4)) << 10) + (i & 15);
    float t1 = 0.f, t2 = 0.f;
#pragma unroll 16
    for (int f = 0; f < FF; ++f) {
        float w = (float)wb[f << 4];
        t1 += w * a[h * 128 + f];
        t2 += w * a[h * 128 + 64 + f];
    }
    cF[h * NN + i]  = __expf(-0.8f * t1);
    E2b[h * NN + i] = (bf16)__expf(t2);
    F2b[h * NN + i] = (bf16)__expf(ALPHA_ * t2);
}

// ---------------------------------------------------------------------------
// Kernel 3 (final, v17): 3-deep ROLLED rotation, scalar den, e1-cancel.
// Best measured total: 79.2us (r30). k_gat latency-bound at ~70-75us floor
// (structural: 32 serial load->VALU->MFMA stages at ~2 blocks/CU residency;
// 7 independent levers all measured 70-75us; no counter near saturation).
// ---------------------------------------------------------------------------
#define DECL_STAGE(P) \
    unsigned P##_bw; \
    bf16x8 P##_ea, P##_fa, P##_b0, P##_b1;

#define LOAD_STAGE(P, s) do { \
    const int jb_ = jwb + ((s) << 4); \
    const bf16* tb_ = whb + ((s) << 10); \
    P##_bw = (unsigned)bitrow16[(s)]; \
    P##_ea = *(const bf16x8*)(e2r + jb_); \
    P##_fa = *(const bf16x8*)(f2r + jb_); \
    P##_b0 = *(const bf16x8*)(tb_ + (l31 << 4) + (lh << 3)); \
    P##_b1 = *(const bf16x8*)(tb_ + ((32 + l31) << 4) + (lh << 3)); \
} while (0)

#define COMPUTE_STAGE(P) do { \
    const unsigned bsel_ = (P##_bw >> sh0) & 0xffu; \
    bf16x8 pa_; \
    _Pragma("unroll") \
    for (int k_ = 0; k_ < 8; ++k_) { \
        float w_ = ((bsel_ >> k_) & 1u) \
                 ? fmaxf((float)P##_ea[k_], c * (float)P##_fa[k_]) : 0.f; \
        den += w_; pa_[k_] = (bf16)w_; \
    } \
    acc0 = __builtin_amdgcn_mfma_f32_32x32x16_bf16(pa_, P##_b0, acc0, 0, 0, 0); \
    acc1 = __builtin_amdgcn_mfma_f32_32x32x16_bf16(pa_, P##_b1, acc1, 0, 0, 0); \
} while (0)

__global__ __launch_bounds__(512, 3) void k_gat(const unsigned* __restrict__ bits,
                                                const bf16* __restrict__ WhTt,
                                                const float* __restrict__ cF,
                                                const bf16* __restrict__ E2b, const bf16* __restrict__ F2b,
                                                const float* __restrict__ bias,
                                                float* __restrict__ out)
{
    __shared__ float red2[2][32][64];    // 16 KB
    __shared__ float dred[8][32];        // 1 KB

    const int bid = blockIdx.x;
    const int hd = bid & 7;              // head 0..7 (== XCD -> L2-local slice)
    const int ib = bid >> 3;             // i-block 0..127

    const int tid = threadIdx.x;
    const int wv  = tid >> 6;            // 0..7 = j-split
    const int l   = tid & 63;
    const int l31 = l & 31;
    const int lh  = l >> 5;

    const int i = (ib << 5) + l31;

    const float c = cF[hd * NN + i];

    f32x16 acc0 = (f32x16)0.f, acc1 = (f32x16)0.f;
    float den = 0.f;

    // 16-bit bit-words: word s covers j = wv*512 + s*16 .. +15
    const unsigned short* bitrow16 =
        (const unsigned short*)(bits + (size_t)i * NW) + (wv << 5);
    const bf16* e2r = E2b + hd * NN;
    const bf16* f2r = F2b + hd * NN;
    // head base of tiled Wh; wave's jblk = wv*32 + s
    const bf16* whb = WhTt + ((size_t)hd << 18) + ((size_t)(wv << 5) << 10);

    const int jwb = (wv << 9) + (lh << 3);   // wave j-base + lane half
    const int sh0 = lh << 3;                 // byte select within 16-bit word

    DECL_STAGE(A); DECL_STAGE(B); DECL_STAGE(C);

    LOAD_STAGE(A, 0); LOAD_STAGE(B, 1);
#pragma unroll 1
    for (int t = 0; t < 10; ++t) {
        LOAD_STAGE(C, 3 * t + 2); COMPUTE_STAGE(A);
        LOAD_STAGE(A, 3 * t + 3); COMPUTE_STAGE(B);
        LOAD_STAGE(B, 3 * t + 4); COMPUTE_STAGE(C);
    }
    COMPUTE_STAGE(A); COMPUTE_STAGE(B);      // stages 30, 31

    // ---- reduction: den ---------------------------------------------------
    den += __shfl_xor(den, 32, 64);
    if (l < 32) dred[wv][l31] = den;

    // ---- acc reduction: 2-buffer pairwise tree ---------------------------
    // C/D layout: col = l&31 (feature), row = (r&3) + 8*(r>>2) + 4*lh (i_loc)
    if (wv < 2) {
        float* rb = &red2[wv][0][0];
#pragma unroll
        for (int g = 0; g < 4; ++g) {
            const int ir = (g << 3) + (lh << 2);
#pragma unroll
            for (int r = 0; r < 4; ++r) {
                rb[(ir + r) * 64 + l31     ] = acc0[4*g + r];
                rb[(ir + r) * 64 + 32 + l31] = acc1[4*g + r];
            }
        }
    }
    __syncthreads();
    if (wv == 2 || wv == 3) {
        float* rb = &red2[wv - 2][0][0];
#pragma unroll
        for (int g = 0; g < 4; ++g) {
            const int ir = (g << 3) + (lh << 2);
#pragma unroll
            for (int r = 0; r < 4; ++r) {
                rb[(ir + r) * 64 + l31     ] += acc0[4*g + r];
                rb[(ir + r) * 64 + 32 + l31] += acc1[4*g + r];
            }
        }
    }
    __syncthreads();
    if (wv == 4 || wv == 5) {
        float* rb = &red2[wv - 4][0][0];
#pragma unroll
        for (int g = 0; g < 4; ++g) {
            const int ir = (g << 3) + (lh << 2);
#pragma unroll
            for (int r = 0; r < 4; ++r) {
                rb[(ir + r) * 64 + l31     ] += acc0[4*g + r];
                rb[(ir + r) * 64 + 32 + l31] += acc1[4*g + r];
            }
        }
    }
    __syncthreads();
    if (wv == 6 || wv == 7) {
        float* rb = &red2[wv - 6][0][0];
#pragma unroll
        for (int g = 0; g < 4; ++g) {
            const int ir = (g << 3) + (lh << 2);
#pragma unroll
            for (int r = 0; r < 4; ++r) {
                rb[(ir + r) * 64 + l31     ] += acc0[4*g + r];
                rb[(ir + r) * 64 + 32 + l31] += acc1[4*g + r];
            }
        }
    }
    __syncthreads();

    // ---- normalize + bias + store (buf0+buf1 folded here) ----------------
    const int iloc = tid >> 4;           // 0..31
    const int c0   = (tid & 15) << 2;    // 0..60, 4 cols per thread
    const float dsum = dred[0][iloc] + dred[1][iloc] + dred[2][iloc] + dred[3][iloc]
                     + dred[4][iloc] + dred[5][iloc] + dred[6][iloc] + dred[7][iloc];
    const float rd = 1.0f / dsum;
    f32x4 o;
#pragma unroll
    for (int r = 0; r < 4; ++r) {
        const float sv = red2[0][iloc][c0 + r] + red2[1][iloc][c0 + r];
        o[r] = sv * rd + bias[(hd << 6) + c0 + r];
    }
    *(f32x4*)&out[(size_t)((ib << 5) + iloc) * HF + (hd << 6) + c0] = o;
}

// ---------------------------------------------------------------------------
extern "C" void kernel_launch(void* const* d_in, const int* in_sizes, int n_in,
                              void* d_out, int out_size, void* d_ws, size_t ws_size,
                              hipStream_t stream) {
    const float* h    = (const float*)d_in[0];
    const int*   adj  = (const int*)d_in[1];
    const float* W    = (const float*)d_in[2];
    const float* a    = (const float*)d_in[3];
    const float* bias = (const float*)d_in[4];
    float* out = (float*)d_out;

    char* ws = (char*)d_ws;
    bf16*     WhTt = (bf16*)ws;                                   // 4 MB tiled
    float*    cF   = (float*)(ws + (size_t)(4 << 20));            // 128 KB
    bf16*     E2b  = (bf16*)(cF + HH * NN);                       // 64 KB
    bf16*     F2b  = E2b + HH * NN;                               // 64 KB
    unsigned* bits = (unsigned*)(ws + (size_t)(4 << 20) + (384 << 10)); // 2 MB

    hipLaunchKernelGGL(k_pack,   dim3(2048), dim3(256), 0, stream, adj, bits);
    hipLaunchKernelGGL(k_wht,    dim3(512),  dim3(256), 0, stream, h, W, WhTt);
    hipLaunchKernelGGL(k_scores, dim3(128),  dim3(256), 0, stream, WhTt, a, cF, E2b, F2b);
    hipLaunchKernelGGL(k_gat,    dim3(1024), dim3(512), 0, stream, bits, WhTt, cF, E2b, F2b, bias, out);
}